// Round 6
// baseline (56189.331 us; speedup 1.0000x reference)
//
#include <hip/hip_runtime.h>

#define SEQ  512
#define IDIM 256
#define HD   1024
#define BT   256
#define NCLS 10

#define NWG  16    // one WG per 16 batch columns -- NO cross-WG communication
#define TPB  512   // 8 waves
#define NW   8     // waves per WG
#define TPW  8     // M-tiles per wave (8 x 16 rows = 128 rows/wave)
#define NKK  40    // processing order: kk' 0..7 = x-part (W_hx), 8..39 = h-part (W_hh)
#define COLS 16

typedef __attribute__((ext_vector_type(8))) short short8;
typedef __attribute__((ext_vector_type(4))) float f32x4;
typedef __attribute__((ext_vector_type(4))) unsigned short us4;

// Weights prepacked in MFMA A-fragment order, stream-sequential per wave:
// g_wpack[w][kk'][j][lane][8]  (bf16). All 16 WGs read the same 2.5MB ->
// stays resident in each XCD's L2.
__device__ unsigned short g_wpack[NW*NKK*TPW*64*8];
__device__ float g_hfinal[NWG][COLS][HD];    // [wg][col][k] fp32, intra-WG only

__device__ __forceinline__ unsigned short f2bf(float f){
    unsigned int u = __builtin_bit_cast(unsigned int, f);
    u += 0x7fffu + ((u >> 16) & 1u);         // round-to-nearest-even
    return (unsigned short)(u >> 16);
}

__device__ __forceinline__ float fast_tanh(float v){
    float e = __expf(2.0f * v);              // exact: tanh = 1 - 2/(e^2v+1)
    return 1.0f - 2.0f / (e + 1.0f);
}

// ---- prepack: W_hx (kk'<8) then W_hh (kk'>=8) into frag-order stream
__global__ __launch_bounds__(256) void prepack(
    const float* __restrict__ w_hx, const float* __restrict__ w_hh)
{
    int id = blockIdx.x*256 + threadIdx.x;    // 640 blocks x 256
    if (id >= NW*NKK*TPW*64) return;
    int ln = id & 63;
    int j  = (id >> 6) & 7;
    int kk = (id >> 9) % NKK;
    int w  = id / (NKK*TPW*64);
    int row = 128*w + 16*j + (ln & 15);
    int ko  = ((ln >> 4) << 3);
    const float* src;
    if (kk < 8)  src = w_hx + (size_t)row*IDIM + kk*32 + ko;
    else         src = w_hh + (size_t)row*HD   + (kk-8)*32 + ko;
    f32x4 v0 = *(const f32x4*)src;
    f32x4 v1 = *(const f32x4*)(src + 4);
    us4 a = { f2bf(v0[0]), f2bf(v0[1]), f2bf(v0[2]), f2bf(v0[3]) };
    us4 b = { f2bf(v1[0]), f2bf(v1[1]), f2bf(v1[2]), f2bf(v1[3]) };
    unsigned short* d = &g_wpack[(size_t)((((w*NKK + kk)*TPW + j)*64 + ln))*8];
    *(us4*)d = a; *(us4*)(d+4) = b;
}

__global__ __launch_bounds__(TPB) void rnn_nosync(
    const float* __restrict__ x, const float* __restrict__ b_h,
    const float* __restrict__ w_ph, const float* __restrict__ b_p,
    float* __restrict__ out)
{
    __shared__ unsigned short Bf[2][32*64*8]; // 64KB: h B-frags, double-buffered

    const int tid = threadIdx.x;
    const int wg  = blockIdx.x;
    const int b0  = wg * COLS;
    const int l   = tid & 63;
    const int w   = tid >> 6;

    // zero B-frag buffer 0  (h_init = 0)
    for (int i = tid; i < 32*64*8/4; i += TPB)
        *(unsigned long long*)&Bf[0][i*4] = 0ull;

    // bias fragments (C/D layout rows)
    f32x4 bias[TPW];
    #pragma unroll
    for (int j = 0; j < TPW; ++j)
        bias[j] = *(const f32x4*)(b_h + 128*w + 16*j + ((l >> 4) << 2));

    const float* xb = x + (size_t)(b0 + (l & 15))*(SEQ*IDIM) + ((l >> 4) << 3);
    const unsigned short* ap = g_wpack + (size_t)w * (NKK*TPW*64*8);
    const int rb = (l >> 4) << 2;             // row offset within tile: 0,4,8,12

    __syncthreads();

    for (int t = 0; t < SEQ; ++t){
        const int p = t & 1;
        const float* xp = xb + (size_t)t * IDIM;

        f32x4 acc[TPW];
        #pragma unroll
        for (int j = 0; j < TPW; ++j) acc[j] = bias[j];

        // x prefetch ring (2-deep), A-stream ring (3-deep)
        f32x4 xv0[2], xv1[2];
        xv0[0] = *(const f32x4*)(xp);       xv1[0] = *(const f32x4*)(xp + 4);
        xv0[1] = *(const f32x4*)(xp + 32);  xv1[1] = *(const f32x4*)(xp + 36);

        short8 Ar[3][TPW];
        #pragma unroll
        for (int q = 0; q < 3; ++q)
            #pragma unroll
            for (int j = 0; j < TPW; ++j)
                Ar[q][j] = *(const short8*)(ap + (size_t)((q*TPW + j)*64 + l)*8);

        #pragma unroll
        for (int kk = 0; kk < NKK; ++kk){
            short8 bfrag;
            if (kk < 8){
                f32x4 v0 = xv0[kk & 1], v1 = xv1[kk & 1];
                short8 bx;
                bx[0]=(short)f2bf(v0[0]); bx[1]=(short)f2bf(v0[1]);
                bx[2]=(short)f2bf(v0[2]); bx[3]=(short)f2bf(v0[3]);
                bx[4]=(short)f2bf(v1[0]); bx[5]=(short)f2bf(v1[1]);
                bx[6]=(short)f2bf(v1[2]); bx[7]=(short)f2bf(v1[3]);
                bfrag = bx;
                if (kk + 2 < 8){               // refill x ring
                    xv0[kk & 1] = *(const f32x4*)(xp + (kk+2)*32);
                    xv1[kk & 1] = *(const f32x4*)(xp + (kk+2)*32 + 4);
                }
            } else {
                bfrag = *(const short8*)&Bf[p][((kk-8)*64 + l)*8];
            }
            #pragma unroll
            for (int j = 0; j < TPW; ++j)
                acc[j] = __builtin_amdgcn_mfma_f32_16x16x32_bf16(
                             Ar[kk % 3][j], bfrag, acc[j], 0, 0, 0);
            if (kk + 3 < NKK){                 // refill A ring
                #pragma unroll
                for (int j = 0; j < TPW; ++j)
                    Ar[kk % 3][j] = *(const short8*)(ap + (size_t)(((kk+3)*TPW + j)*64 + l)*8);
            }
        }

        // activation; write h_{t+1} B-frags to the other LDS buffer
        #pragma unroll
        for (int j = 0; j < TPW; ++j){
            const int tm = w*TPW + j;          // 0..63
            float h0 = fast_tanh(acc[j][0]);
            float h1 = fast_tanh(acc[j][1]);
            float h2 = fast_tanh(acc[j][2]);
            float h3 = fast_tanh(acc[j][3]);
            if (t < SEQ-1){
                int kkd  = tm >> 1;
                int base = 16*(tm & 1) + rb;   // 0..28, step 4
                int lnp  = (l & 15) | (((base >> 3) & 3) << 4);
                us4 hw = { f2bf(h0), f2bf(h1), f2bf(h2), f2bf(h3) };
                *(us4*)&Bf[p ^ 1][(kkd*64 + lnp)*8 + (base & 4)] = hw;
            } else {
                f32x4 hf = {h0, h1, h2, h3};
                *(f32x4*)&g_hfinal[wg][l & 15][16*tm + rb] = hf;
            }
        }
        __syncthreads();   // drains LDS writes (and final global stores)
    }

    // ---- projection for this WG's 16 columns: out[b][c] = w_ph @ h + b_p
    if (tid < NCLS*COLS){
        const int c   = tid / COLS;
        const int col = tid % COLS;
        const float* hp = &g_hfinal[wg][col][0];
        const float* wp = w_ph + (size_t)c * HD;
        float s = b_p[c];
        for (int k = 0; k < HD; k += 4){
            f32x4 hv = *(const f32x4*)(hp + k);
            f32x4 wv = *(const f32x4*)(wp + k);
            s += hv[0]*wv[0] + hv[1]*wv[1] + hv[2]*wv[2] + hv[3]*wv[3];
        }
        out[(size_t)(b0 + col)*NCLS + c] = s;
    }
}

extern "C" void kernel_launch(void* const* d_in, const int* in_sizes, int n_in,
                              void* d_out, int out_size, void* d_ws, size_t ws_size,
                              hipStream_t stream) {
    const float* x    = (const float*)d_in[0];
    const float* w_hx = (const float*)d_in[1];
    const float* w_hh = (const float*)d_in[2];
    const float* b_h  = (const float*)d_in[3];
    const float* w_ph = (const float*)d_in[4];
    const float* b_p  = (const float*)d_in[5];

    prepack<<<dim3(640), dim3(256), 0, stream>>>(w_hx, w_hh);
    rnn_nosync<<<dim3(NWG), dim3(TPB), 0, stream>>>(x, b_h, w_ph, b_p, (float*)d_out);
}

// Round 7
// 2994.935 us; speedup vs baseline: 18.7615x; 18.7615x over previous
//
#include <hip/hip_runtime.h>

#define SEQ  512
#define IDIM 256
#define HD   1024
#define BT   256
#define NCLS 10

#define GR   8     // row groups (128 rows each)
#define GB   16    // batch groups (16 cols each)
#define NWG  (GR*GB)   // 128 WGs
#define TPB  512       // 8 waves
#define KKH  32        // h kk-blocks (K=1024)
#define KKX  8         // x kk-blocks (K=256)

typedef __attribute__((ext_vector_type(8))) short short8;
typedef __attribute__((ext_vector_type(4))) float f32x4;
typedef __attribute__((ext_vector_type(4))) unsigned short us4;
typedef __attribute__((ext_vector_type(4))) int i32x4;

// h double buffer, B-fragment order per col-group:
// g_h[buf][gbg][kk*512 + lane*8 + i] ; k = kk*32 + (lane>>4)*8 + i, col = lane&15
// All cross-WG traffic via system-scope (sc0+sc1) ops at the LLC --
// correct regardless of WG->XCD placement (R5-proven protocol).
__device__ unsigned short g_h[2][GB][KKH*64*8];
__device__ float g_hfinal[BT][HD];
__device__ int g_flag[GB][16];            // 8 used, 64B-aligned per group
__device__ unsigned int g_done[GB*16];    // padded done counters

__device__ __forceinline__ unsigned short f2bf(float f){
    unsigned int u = __builtin_bit_cast(unsigned int, f);
    u += 0x7fffu + ((u >> 16) & 1u);      // round-to-nearest-even
    return (unsigned short)(u >> 16);
}

__device__ __forceinline__ float fast_tanh(float v){
    float e = __expf(2.0f * v);           // exact: tanh = 1 - 2/(e^2v+1)
    return 1.0f - 2.0f / (e + 1.0f);
}

__device__ __forceinline__ void sys_st64(unsigned short* p, unsigned long long v){
    __hip_atomic_store((unsigned long long*)p, v, __ATOMIC_RELAXED, __HIP_MEMORY_SCOPE_SYSTEM);
}
__device__ __forceinline__ void sys_st32(int* p, int v){
    __hip_atomic_store(p, v, __ATOMIC_RELAXED, __HIP_MEMORY_SCOPE_SYSTEM);
}
__device__ __forceinline__ int sys_ld32(const int* p){
    return __hip_atomic_load(p, __ATOMIC_RELAXED, __HIP_MEMORY_SCOPE_SYSTEM);
}

__global__ __launch_bounds__(TPB, 1) void rnn_main(
    const float* __restrict__ x, const float* __restrict__ w_hx,
    const float* __restrict__ w_hh, const float* __restrict__ b_h)
{
    __shared__ unsigned short sB[KKH*64*8];   // 32 KB: staged h slab (B-frag order)

    const int tid = threadIdx.x;
    const int wg  = blockIdx.x;
    const int gbg = wg & (GB-1);
    const int gr  = wg >> 4;
    const int r0  = gr * 128;
    const int b0  = gbg * 16;
    const int l   = tid & 63;
    const int w   = tid >> 6;               // wave 0..7 = row-tile
    const int rw  = r0 + w*16;              // this wave's 16 rows
    const int row = rw + (l & 15);
    const int ko  = (l >> 4) << 3;          // k offset within kk-block

    // ---- hoist weights into registers (A-frag order; bijection proven R1-R6)
    short8 wa[40];
    #pragma unroll
    for (int kk = 0; kk < KKH; ++kk){
        f32x4 v0 = *(const f32x4*)(w_hh + (size_t)row*HD + kk*32 + ko);
        f32x4 v1 = *(const f32x4*)(w_hh + (size_t)row*HD + kk*32 + ko + 4);
        short8 a;
        a[0]=(short)f2bf(v0[0]); a[1]=(short)f2bf(v0[1]);
        a[2]=(short)f2bf(v0[2]); a[3]=(short)f2bf(v0[3]);
        a[4]=(short)f2bf(v1[0]); a[5]=(short)f2bf(v1[1]);
        a[6]=(short)f2bf(v1[2]); a[7]=(short)f2bf(v1[3]);
        wa[kk] = a;
    }
    #pragma unroll
    for (int xk = 0; xk < KKX; ++xk){
        f32x4 v0 = *(const f32x4*)(w_hx + (size_t)row*IDIM + xk*32 + ko);
        f32x4 v1 = *(const f32x4*)(w_hx + (size_t)row*IDIM + xk*32 + ko + 4);
        short8 a;
        a[0]=(short)f2bf(v0[0]); a[1]=(short)f2bf(v0[1]);
        a[2]=(short)f2bf(v0[2]); a[3]=(short)f2bf(v0[3]);
        a[4]=(short)f2bf(v1[0]); a[5]=(short)f2bf(v1[1]);
        a[6]=(short)f2bf(v1[2]); a[7]=(short)f2bf(v1[3]);
        wa[KKH + xk] = a;
    }

    const f32x4 bias = *(const f32x4*)(b_h + rw + ((l >> 4) << 2));
    const float* xlane = x + (size_t)(b0 + (l & 15))*(SEQ*IDIM) + ko;

    // ---- zero our kk-range of buf0 (h_init = 0): 4 KB per WG, sc1 stores
    {
        int kkz = gr*4 + (tid >> 7);         // 4 kk-blocks per WG
        int rem = tid & 127;                 // 128 threads x 8B per kk-block
        sys_st64(&g_h[0][gbg][(size_t)kkz*512 + rem*4], 0ull);
    }
    asm volatile("s_waitcnt vmcnt(0)" ::: "memory");
    __syncthreads();
    if (tid == 0) sys_st32(&g_flag[gbg][gr], 1);   // buf0 published

    for (int t = 0; t < SEQ; ++t){
        const int rb = t & 1;
        f32x4 acc = bias;

        // ---- x-part first (independent of h): overlaps producer latency
        const float* xp = xlane + (size_t)t*IDIM;
        #pragma unroll
        for (int xk = 0; xk < KKX; ++xk){
            f32x4 v0 = *(const f32x4*)(xp + xk*32);
            f32x4 v1 = *(const f32x4*)(xp + xk*32 + 4);
            short8 bx;
            bx[0]=(short)f2bf(v0[0]); bx[1]=(short)f2bf(v0[1]);
            bx[2]=(short)f2bf(v0[2]); bx[3]=(short)f2bf(v0[3]);
            bx[4]=(short)f2bf(v1[0]); bx[5]=(short)f2bf(v1[1]);
            bx[6]=(short)f2bf(v1[2]); bx[7]=(short)f2bf(v1[3]);
            acc = __builtin_amdgcn_mfma_f32_16x16x32_bf16(wa[KKH+xk], bx, acc, 0, 0, 0);
        }

        // ---- wait: wave 0 polls the 8 producer flags of this col-group
        if (w == 0){
            const int val = t + 1;
            int guard = 0;
            for (;;){
                int f = sys_ld32(&g_flag[gbg][l & 7]);
                if (__all(f >= val)) break;
                if (++guard > (1 << 20)) break;   // hang safety
            }
        }
        __syncthreads();

        // ---- stage h slab (32 KB) once per WG: wave w covers kk [w*4, w*4+4)
        const unsigned short* slab = &g_h[rb][gbg][0];
        i32x4 st[4];
        #pragma unroll
        for (int c = 0; c < 4; ++c){
            const unsigned short* p = slab + (size_t)((w*4 + c)*64 + l)*8;
            asm volatile("global_load_dwordx4 %0, %1, off sc0 sc1" : "=v"(st[c]) : "v"(p));
        }
        asm volatile("s_waitcnt vmcnt(0)" ::: "memory");
        #pragma unroll
        for (int c = 0; c < 4; ++c)
            *(i32x4*)&sB[(size_t)((w*4 + c)*64 + l)*8] = st[c];
        __syncthreads();

        // ---- recurrent part: K = 1024, B-frags from LDS, A from registers
        #pragma unroll
        for (int kk = 0; kk < KKH; ++kk){
            short8 b = *(const short8*)&sB[(size_t)(kk*64 + l)*8];
            acc = __builtin_amdgcn_mfma_f32_16x16x32_bf16(wa[kk], b, acc, 0, 0, 0);
        }

        float h0 = fast_tanh(acc[0]);
        float h1 = fast_tanh(acc[1]);
        float h2 = fast_tanh(acc[2]);
        float h3 = fast_tanh(acc[3]);

        // ---- write h_{t+1} fragment (B-frag order) to the other buffer
        const int rloc = w*16 + ((l >> 4) << 2);          // 0..124
        if (t < SEQ-1){
            int kkd = gr*4 + (rloc >> 5);
            int lnp = (l & 15) | (((rloc >> 3) & 3) << 4);
            us4 hw = { f2bf(h0), f2bf(h1), f2bf(h2), f2bf(h3) };
            sys_st64(&g_h[rb ^ 1][gbg][(size_t)kkd*512 + lnp*8 + (rloc & 7)],
                     __builtin_bit_cast(unsigned long long, hw));
            asm volatile("s_waitcnt vmcnt(0)" ::: "memory");
            __syncthreads();                               // all 8 waves' h drained
            if (tid == 0) sys_st32(&g_flag[gbg][gr], t + 2);
        } else {
            f32x4 hf = {h0, h1, h2, h3};
            *(f32x4*)&g_hfinal[b0 + (l & 15)][r0 + rloc] = hf;
        }
    }

    // ---- epilogue: race-free flag reset for graph replay
    __syncthreads();
    if (tid == 0){
        __hip_atomic_fetch_add(&g_done[gbg*16], 1u, __ATOMIC_ACQ_REL, __HIP_MEMORY_SCOPE_SYSTEM);
        if (gr == 0){
            int guard = 0;
            while (__hip_atomic_load(&g_done[gbg*16], __ATOMIC_ACQUIRE, __HIP_MEMORY_SCOPE_SYSTEM) < GR
                   && ++guard < (1 << 22)) { }
            for (int i = 0; i < GR; ++i)
                sys_st32(&g_flag[gbg][i], 0);
            __hip_atomic_store(&g_done[gbg*16], 0u, __ATOMIC_RELAXED, __HIP_MEMORY_SCOPE_SYSTEM);
        }
    }
}

// p = w_ph @ h_final + b_p ; out[b][c]
__global__ __launch_bounds__(256, 1) void proj_kernel(
    const float* __restrict__ w_ph, const float* __restrict__ b_p, float* __restrict__ out)
{
    const int b   = blockIdx.x;
    const int tid = threadIdx.x;
    const int l   = tid & 63;
    const int wv  = tid >> 6;
    __shared__ float red[4];
    f32x4 hv = *(const f32x4*)(&g_hfinal[b][0] + tid*4);
    for (int c = 0; c < NCLS; ++c){
        f32x4 wvv = *(const f32x4*)(w_ph + c*HD + tid*4);
        float s = hv[0]*wvv[0] + hv[1]*wvv[1] + hv[2]*wvv[2] + hv[3]*wvv[3];
        #pragma unroll
        for (int off = 32; off; off >>= 1) s += __shfl_down(s, off, 64);
        if (l == 0) red[wv] = s;
        __syncthreads();
        if (tid == 0) out[b*NCLS + c] = red[0] + red[1] + red[2] + red[3] + b_p[c];
        __syncthreads();
    }
}

extern "C" void kernel_launch(void* const* d_in, const int* in_sizes, int n_in,
                              void* d_out, int out_size, void* d_ws, size_t ws_size,
                              hipStream_t stream) {
    const float* x    = (const float*)d_in[0];
    const float* w_hx = (const float*)d_in[1];
    const float* w_hh = (const float*)d_in[2];
    const float* b_h  = (const float*)d_in[3];
    const float* w_ph = (const float*)d_in[4];
    const float* b_p  = (const float*)d_in[5];

    void* args[] = { (void*)&x, (void*)&w_hx, (void*)&w_hh, (void*)&b_h };
    hipError_t err = hipLaunchCooperativeKernel((void*)rnn_main, dim3(NWG), dim3(TPB),
                                                args, 0, stream);
    if (err != hipSuccess) {
        rnn_main<<<dim3(NWG), dim3(TPB), 0, stream>>>(x, w_hx, w_hh, b_h);
    }
    proj_kernel<<<dim3(BT), dim3(256), 0, stream>>>(w_ph, b_p, (float*)d_out);
}

// Round 8
// 2848.501 us; speedup vs baseline: 19.7259x; 1.0514x over previous
//
#include <hip/hip_runtime.h>

#define SEQ  512
#define IDIM 256
#define HD   1024
#define BT   256
#define NCLS 10

#define GR   8         // row groups (128 rows each)
#define GB   16        // batch groups (16 cols each)
#define ACT  (GR*GB)   // 128 active WGs
#define NLW  256       // launched WGs (1 per CU); extras exit after discovery
#define TPB  512       // 8 waves
#define KKH  32        // h kk-blocks (K=1024)
#define KKX  8         // x kk-blocks (K=256)

typedef __attribute__((ext_vector_type(8))) short short8;
typedef __attribute__((ext_vector_type(4))) float f32x4;
typedef __attribute__((ext_vector_type(4))) unsigned short us4;
typedef __attribute__((ext_vector_type(4))) int i32x4;

// h double buffer, B-fragment order per col-group (R7 layout).
// FAST mode: one col-group == 8 WGs on ONE XCD (verified by ping at launch);
//            h+flags via plain stores + sc0 loads through that XCD's L2.
// SLOW mode: R7-proven sc1 (LLC) protocol, placement-independent.
__device__ unsigned short g_h[2][GB][KKH*64*8];
__device__ float g_hfinal[BT][HD];
__device__ int g_sflag[GB][16];            // slow-path flags (LLC)
__device__ __align__(64) int g_fflag[GB][16];  // fast-path flags (XCD L2)
__device__ __align__(64) int g_token[GB][16];  // ping tokens (XCD L2)
__device__ unsigned g_xcnt[8*16];          // per-XCD claim counters (padded)
__device__ unsigned g_gdone[GB*16];        // per-group done (padded, LLC)
__device__ unsigned g_bar1, g_bar2, g_fail, g_done_all;

__device__ __forceinline__ unsigned short f2bf(float f){
    unsigned int u = __builtin_bit_cast(unsigned int, f);
    u += 0x7fffu + ((u >> 16) & 1u);      // round-to-nearest-even
    return (unsigned short)(u >> 16);
}
__device__ __forceinline__ float fast_tanh(float v){
    float e = __expf(2.0f * v);           // exact: tanh = 1 - 2/(e^2v+1)
    return 1.0f - 2.0f / (e + 1.0f);
}
__device__ __forceinline__ void sys_st64(unsigned short* p, unsigned long long v){
    __hip_atomic_store((unsigned long long*)p, v, __ATOMIC_RELAXED, __HIP_MEMORY_SCOPE_SYSTEM);
}
__device__ __forceinline__ void sys_st32(int* p, int v){
    __hip_atomic_store(p, v, __ATOMIC_RELAXED, __HIP_MEMORY_SCOPE_SYSTEM);
}
__device__ __forceinline__ int sys_ld32(const int* p){
    return __hip_atomic_load(p, __ATOMIC_RELAXED, __HIP_MEMORY_SCOPE_SYSTEM);
}

template<bool FAST>
__device__ __forceinline__ void rnn_loop(
    int gbg, int gr, int tid,
    const float* __restrict__ x, const float* __restrict__ w_hx,
    const float* __restrict__ w_hh, const float* __restrict__ b_h,
    unsigned short* sB)
{
    const int l   = tid & 63;
    const int w   = tid >> 6;
    const int r0  = gr * 128;
    const int b0  = gbg * 16;
    const int rw  = r0 + w*16;
    const int row = rw + (l & 15);
    const int ko  = (l >> 4) << 3;

    // ---- weights -> registers (A-frag order; bijection proven R1-R7)
    short8 wa[40];
    #pragma unroll
    for (int kk = 0; kk < KKH; ++kk){
        f32x4 v0 = *(const f32x4*)(w_hh + (size_t)row*HD + kk*32 + ko);
        f32x4 v1 = *(const f32x4*)(w_hh + (size_t)row*HD + kk*32 + ko + 4);
        short8 a;
        a[0]=(short)f2bf(v0[0]); a[1]=(short)f2bf(v0[1]);
        a[2]=(short)f2bf(v0[2]); a[3]=(short)f2bf(v0[3]);
        a[4]=(short)f2bf(v1[0]); a[5]=(short)f2bf(v1[1]);
        a[6]=(short)f2bf(v1[2]); a[7]=(short)f2bf(v1[3]);
        wa[kk] = a;
    }
    #pragma unroll
    for (int xk = 0; xk < KKX; ++xk){
        f32x4 v0 = *(const f32x4*)(w_hx + (size_t)row*IDIM + xk*32 + ko);
        f32x4 v1 = *(const f32x4*)(w_hx + (size_t)row*IDIM + xk*32 + ko + 4);
        short8 a;
        a[0]=(short)f2bf(v0[0]); a[1]=(short)f2bf(v0[1]);
        a[2]=(short)f2bf(v0[2]); a[3]=(short)f2bf(v0[3]);
        a[4]=(short)f2bf(v1[0]); a[5]=(short)f2bf(v1[1]);
        a[6]=(short)f2bf(v1[2]); a[7]=(short)f2bf(v1[3]);
        wa[KKH + xk] = a;
    }

    const f32x4 bias = *(const f32x4*)(b_h + rw + ((l >> 4) << 2));
    const float* xlane = x + (size_t)(b0 + (l & 15))*(SEQ*IDIM) + ko;

    // ---- zero our kk-range of buf0 (h_init = 0)
    {
        int kkz = gr*4 + (tid >> 7);
        int rem = tid & 127;
        unsigned short* zp = &g_h[0][gbg][(size_t)kkz*512 + rem*4];
        if (FAST){
            unsigned long long z = 0;
            asm volatile("global_store_dwordx2 %0, %1, off" :: "v"(zp), "v"(z) : "memory");
        } else sys_st64(zp, 0ull);
    }
    asm volatile("s_waitcnt vmcnt(0)" ::: "memory");
    __syncthreads();
    int* const myflag = FAST ? &g_fflag[gbg][gr] : &g_sflag[gbg][gr];
    const int* const fl = FAST ? &g_fflag[gbg][0] : &g_sflag[gbg][0];
    if (tid == 0){
        if (FAST){ int one = 1;
            asm volatile("global_store_dword %0, %1, off" :: "v"(myflag), "v"(one) : "memory");
        } else sys_st32(myflag, 1);
    }

    for (int t = 0; t < SEQ; ++t){
        const int rb = t & 1;
        f32x4 acc = bias;

        // ---- x-part first (independent of h): overlaps producer latency
        const float* xp = xlane + (size_t)t*IDIM;
        #pragma unroll
        for (int xk = 0; xk < KKX; ++xk){
            f32x4 v0 = *(const f32x4*)(xp + xk*32);
            f32x4 v1 = *(const f32x4*)(xp + xk*32 + 4);
            short8 bx;
            bx[0]=(short)f2bf(v0[0]); bx[1]=(short)f2bf(v0[1]);
            bx[2]=(short)f2bf(v0[2]); bx[3]=(short)f2bf(v0[3]);
            bx[4]=(short)f2bf(v1[0]); bx[5]=(short)f2bf(v1[1]);
            bx[6]=(short)f2bf(v1[2]); bx[7]=(short)f2bf(v1[3]);
            acc = __builtin_amdgcn_mfma_f32_16x16x32_bf16(wa[KKH+xk], bx, acc, 0, 0, 0);
        }

        // ---- wait: wave 0 polls the 8 producer flags of this col-group
        if (w == 0){
            const int val = t + 1;
            const int* pp = fl + (l & 7);
            int guard = 0;
            for (;;){
                int f;
                if (FAST){
                    asm volatile("global_load_dword %0, %1, off sc0" : "=&v"(f) : "v"(pp));
                    asm volatile("s_waitcnt vmcnt(0)" ::: "memory");
                } else f = sys_ld32(pp);
                if (__all(f >= val)) break;
                if (++guard > (1 << 20)) break;   // hang safety
            }
        }
        __syncthreads();

        // ---- stage h slab (32 KB) once per WG: wave w covers kk [w*4, w*4+4)
        const unsigned short* slab = &g_h[rb][gbg][0];
        i32x4 st[4];
        #pragma unroll
        for (int c = 0; c < 4; ++c){
            const unsigned short* p = slab + (size_t)((w*4 + c)*64 + l)*8;
            if (FAST)
                asm volatile("global_load_dwordx4 %0, %1, off sc0"     : "=v"(st[c]) : "v"(p));
            else
                asm volatile("global_load_dwordx4 %0, %1, off sc0 sc1" : "=v"(st[c]) : "v"(p));
        }
        asm volatile("s_waitcnt vmcnt(0)" ::: "memory");
        #pragma unroll
        for (int c = 0; c < 4; ++c)
            *(i32x4*)&sB[(size_t)((w*4 + c)*64 + l)*8] = st[c];
        __syncthreads();

        // ---- recurrent part: K = 1024, B-frags from LDS, A from registers
        #pragma unroll
        for (int kk = 0; kk < KKH; ++kk){
            short8 b = *(const short8*)&sB[(size_t)(kk*64 + l)*8];
            acc = __builtin_amdgcn_mfma_f32_16x16x32_bf16(wa[kk], b, acc, 0, 0, 0);
        }

        float h0 = fast_tanh(acc[0]);
        float h1 = fast_tanh(acc[1]);
        float h2 = fast_tanh(acc[2]);
        float h3 = fast_tanh(acc[3]);

        const int rloc = w*16 + ((l >> 4) << 2);
        if (t < SEQ-1){
            int kkd = gr*4 + (rloc >> 5);
            int lnp = (l & 15) | (((rloc >> 3) & 3) << 4);
            us4 hw = { f2bf(h0), f2bf(h1), f2bf(h2), f2bf(h3) };
            unsigned long long hbits = __builtin_bit_cast(unsigned long long, hw);
            unsigned short* hp = &g_h[rb ^ 1][gbg][(size_t)kkd*512 + lnp*8 + (rloc & 7)];
            if (FAST)
                asm volatile("global_store_dwordx2 %0, %1, off" :: "v"(hp), "v"(hbits) : "memory");
            else sys_st64(hp, hbits);
            asm volatile("s_waitcnt vmcnt(0)" ::: "memory");
            __syncthreads();
            if (tid == 0){
                int v2 = t + 2;
                if (FAST)
                    asm volatile("global_store_dword %0, %1, off" :: "v"(myflag), "v"(v2) : "memory");
                else sys_st32(myflag, v2);
            }
        } else {
            f32x4 hf = {h0, h1, h2, h3};
            *(f32x4*)&g_hfinal[b0 + (l & 15)][r0 + rloc] = hf;
        }
    }

    // ---- FAST group cleanup: owners zero their own (L2-dirty) flag lines
    if (FAST && tid == 0){
        __hip_atomic_fetch_add(&g_gdone[gbg*16], 1u, __ATOMIC_ACQ_REL, __HIP_MEMORY_SCOPE_SYSTEM);
        if (gr == 0){
            int guard = 0;
            while (__hip_atomic_load(&g_gdone[gbg*16], __ATOMIC_ACQUIRE, __HIP_MEMORY_SCOPE_SYSTEM) < GR
                   && ++guard < (1 << 22)) { }
            for (int i = 0; i < 16; ++i){
                int z = 0; int* p = &g_fflag[gbg][i];
                asm volatile("global_store_dword %0, %1, off" :: "v"(p), "v"(z) : "memory");
            }
            __hip_atomic_store(&g_gdone[gbg*16], 0u, __ATOMIC_RELAXED, __HIP_MEMORY_SCOPE_SYSTEM);
        }
    }
}

__global__ __launch_bounds__(TPB)
__attribute__((amdgpu_waves_per_eu(2, 2)))
void rnn_main(
    const float* __restrict__ x, const float* __restrict__ w_hx,
    const float* __restrict__ w_hh, const float* __restrict__ b_h)
{
    __shared__ unsigned short sB[KKH*64*8];   // 32 KB staged h slab
    __shared__ int s_role, s_fail;

    const int tid = threadIdx.x;
    const int bid = blockIdx.x;
    const int l   = tid & 63;
    const int w   = tid >> 6;

    // ---- claim a role on this WG's XCD; publish ping token; grid barrier 1
    if (tid == 0){
        unsigned xcd;
        asm volatile("s_getreg_b32 %0, hwreg(20, 0, 4)" : "=s"(xcd));
        xcd &= 7u;
        unsigned r = __hip_atomic_fetch_add(&g_xcnt[xcd*16], 1u,
                          __ATOMIC_RELAXED, __HIP_MEMORY_SCOPE_SYSTEM);
        int role = (r < 16u) ? (int)(xcd*16u + r) : -1;
        s_role = role;
        if (role >= 0){
            int one = 1; int* tp = &g_token[role >> 3][role & 7];
            asm volatile("global_store_dword %0, %1, off" :: "v"(tp), "v"(one) : "memory");
            asm volatile("s_waitcnt vmcnt(0)" ::: "memory");
        }
        __hip_atomic_fetch_add(&g_bar1, 1u, __ATOMIC_ACQ_REL, __HIP_MEMORY_SCOPE_SYSTEM);
        int guard = 0;
        while (__hip_atomic_load(&g_bar1, __ATOMIC_ACQUIRE, __HIP_MEMORY_SCOPE_SYSTEM) < NLW
               && ++guard < (1 << 22)) { }
    }
    __syncthreads();
    const int role = s_role;

    // ---- ping: verify the EXACT steady-state mechanism among claimed peers
    if (w == 0 && role >= 0){
        const int pg = role >> 3;
        int ok, guard = 0;
        for (;;){
            int f = 1;
            if (l < 8){
                const int* tp = &g_token[pg][l];
                asm volatile("global_load_dword %0, %1, off sc0" : "=&v"(f) : "v"(tp));
                asm volatile("s_waitcnt vmcnt(0)" ::: "memory");
            }
            ok = __all(f != 0);
            if (ok || ++guard > (1 << 13)) break;
        }
        if (tid == 0 && !ok)
            __hip_atomic_fetch_add(&g_fail, 1u, __ATOMIC_ACQ_REL, __HIP_MEMORY_SCOPE_SYSTEM);
    }
    __syncthreads();
    // ---- grid barrier 2; then read verdict; owners reset own tokens
    if (tid == 0){
        __hip_atomic_fetch_add(&g_bar2, 1u, __ATOMIC_ACQ_REL, __HIP_MEMORY_SCOPE_SYSTEM);
        int guard = 0;
        while (__hip_atomic_load(&g_bar2, __ATOMIC_ACQUIRE, __HIP_MEMORY_SCOPE_SYSTEM) < NLW
               && ++guard < (1 << 22)) { }
        s_fail = (int)__hip_atomic_load(&g_fail, __ATOMIC_ACQUIRE, __HIP_MEMORY_SCOPE_SYSTEM);
        if (role >= 0){
            int z = 0; int* tp = &g_token[role >> 3][role & 7];
            asm volatile("global_store_dword %0, %1, off" :: "v"(tp), "v"(z) : "memory");
        }
    }
    __syncthreads();
    const int fail = s_fail;

    bool active, fastm;
    int gbg, gr;
    if (fail == 0){ fastm = true;  active = (role >= 0); gbg = role >> 3; gr = role & 7; }
    else          { fastm = false; active = (bid < ACT); gbg = bid & 15;  gr = bid >> 4; }

    if (!active) return;

    if (fastm) rnn_loop<true >(gbg, gr, tid, x, w_hx, w_hh, b_h, sB);
    else       rnn_loop<false>(gbg, gr, tid, x, w_hx, w_hh, b_h, sB);

    // ---- global epilogue: last active WG resets LLC-side coordination state
    __syncthreads();
    if (tid == 0){
        unsigned old = __hip_atomic_fetch_add(&g_done_all, 1u,
                           __ATOMIC_ACQ_REL, __HIP_MEMORY_SCOPE_SYSTEM);
        if (old == ACT - 1){
            for (int g = 0; g < GB; ++g)
                for (int i = 0; i < 16; ++i) sys_st32(&g_sflag[g][i], 0);
            for (int i = 0; i < 8; ++i)
                __hip_atomic_store(&g_xcnt[i*16], 0u, __ATOMIC_RELAXED, __HIP_MEMORY_SCOPE_SYSTEM);
            __hip_atomic_store(&g_fail, 0u, __ATOMIC_RELAXED, __HIP_MEMORY_SCOPE_SYSTEM);
            __hip_atomic_store(&g_bar1, 0u, __ATOMIC_RELAXED, __HIP_MEMORY_SCOPE_SYSTEM);
            __hip_atomic_store(&g_bar2, 0u, __ATOMIC_RELAXED, __HIP_MEMORY_SCOPE_SYSTEM);
            __hip_atomic_store(&g_done_all, 0u, __ATOMIC_RELAXED, __HIP_MEMORY_SCOPE_SYSTEM);
        }
    }
}

// p = w_ph @ h_final + b_p ; out[b][c]
__global__ __launch_bounds__(256, 1) void proj_kernel(
    const float* __restrict__ w_ph, const float* __restrict__ b_p, float* __restrict__ out)
{
    const int b   = blockIdx.x;
    const int tid = threadIdx.x;
    const int l   = tid & 63;
    const int wv  = tid >> 6;
    __shared__ float red[4];
    f32x4 hv = *(const f32x4*)(&g_hfinal[b][0] + tid*4);
    for (int c = 0; c < NCLS; ++c){
        f32x4 wvv = *(const f32x4*)(w_ph + c*HD + tid*4);
        float s = hv[0]*wvv[0] + hv[1]*wvv[1] + hv[2]*wvv[2] + hv[3]*wvv[3];
        #pragma unroll
        for (int off = 32; off; off >>= 1) s += __shfl_down(s, off, 64);
        if (l == 0) red[wv] = s;
        __syncthreads();
        if (tid == 0) out[b*NCLS + c] = red[0] + red[1] + red[2] + red[3] + b_p[c];
        __syncthreads();
    }
}

extern "C" void kernel_launch(void* const* d_in, const int* in_sizes, int n_in,
                              void* d_out, int out_size, void* d_ws, size_t ws_size,
                              hipStream_t stream) {
    const float* x    = (const float*)d_in[0];
    const float* w_hx = (const float*)d_in[1];
    const float* w_hh = (const float*)d_in[2];
    const float* b_h  = (const float*)d_in[3];
    const float* w_ph = (const float*)d_in[4];
    const float* b_p  = (const float*)d_in[5];

    void* args[] = { (void*)&x, (void*)&w_hx, (void*)&w_hh, (void*)&b_h };
    hipError_t err = hipLaunchCooperativeKernel((void*)rnn_main, dim3(NLW), dim3(TPB),
                                                args, 0, stream);
    if (err != hipSuccess) {
        rnn_main<<<dim3(NLW), dim3(TPB), 0, stream>>>(x, w_hx, w_hh, b_h);
    }
    proj_kernel<<<dim3(BT), dim3(256), 0, stream>>>(w_ph, b_p, (float*)d_out);
}